// Round 2
// 144.732 us; speedup vs baseline: 1.0780x; 1.0780x over previous
//
#include <hip/hip_runtime.h>

// Problem constants (fixed by the reference's setup_inputs)
#define C_DIM 64
#define P_DIM 16
#define K_DIM 9            // K1*K1
#define PK (P_DIM * K_DIM) // 144
#define INV2S 0.35355339059327373f  // 1/(2*sqrt(2))

typedef __attribute__((ext_vector_type(8))) short short8v;  // 8 bf16 (4 VGPRs)
typedef __attribute__((ext_vector_type(4))) float f32x4;    // MFMA accumulator

__device__ __forceinline__ ushort f2bf(float f) {
    uint u = __builtin_bit_cast(uint, f);
    return (ushort)((u + 0x7FFFu + ((u >> 16) & 1u)) >> 16);   // RNE
}
__device__ __forceinline__ float bf2f(ushort h) {
    return __builtin_bit_cast(float, ((uint)h) << 16);
}

// LDS row stride (in ushorts) for the W hi/lo tables: 72*2B = 144B rows,
// 16B aligned, bank stride 36 (=4 mod 32) -> <=2-way on b128 reads.
#define ZSTRIDE 72

// ---------------------------------------------------------------------------
// Kernel 1 (MFMA): (a) bias-init out, (b) [optional] pose -> packed-bf16,
// (c) Zb[n, p*9+k] = sum_c x[n,c] * W[p,k,c] via split-bf16 3-product MFMA.
// Block = 64 rows, 4 waves; wave w owns rows w*16..w*16+15, all 9 n-tiles.
// A frags come straight from global x (8 contiguous floats/lane/chunk);
// B frags from LDS-staged bf16 hi/lo W tables (converted once per block).
// A/B k-packing is the same bijection for both operands, so the contraction
// is correct independent of the HW's internal k ordering; C/D mapping is
// the HW-verified col=lane&15, row=(lane>>4)*4+reg.
// ---------------------------------------------------------------------------
__global__ __launch_bounds__(256) void z_gemm_kernel(const float* __restrict__ x,
                                                     const float* __restrict__ W,
                                                     const float* __restrict__ bias,
                                                     const float* __restrict__ pose,
                                                     float* __restrict__ out,
                                                     ushort* __restrict__ Zb,
                                                     uint* __restrict__ pose_bf,
                                                     int N) {
    __shared__ ushort w_hi[PK * ZSTRIDE];   // 20736 B
    __shared__ ushort w_lo[PK * ZSTRIDE];   // 20736 B

    const int tid = threadIdx.x;
    const int block_row = blockIdx.x * 64;

    // (a) bias-init this block's slice of out: 64 rows x 16 = 256 float4s
    {
        const float4 b4 = ((const float4*)bias)[tid & 3];
        const int o4 = block_row * 4 + tid;          // float4 index into out
        if (o4 < N * 4) ((float4*)out)[o4] = b4;
    }

    // (b) pose -> packed bf16 (only when workspace has room for the table)
    if (pose_bf != nullptr) {
        for (int i = tid; i < 64 * P_DIM; i += 256) {
            const int r = block_row + (i >> 4);
            if (r < N) {
                const float2 ab = ((const float2*)pose)[(size_t)r * P_DIM + (i & 15)];
                pose_bf[(size_t)r * P_DIM + (i & 15)] =
                    (uint)f2bf(ab.x) | ((uint)f2bf(ab.y) << 16);
            }
        }
    }

    // (c) stage W (144x64 f32) as hi/lo bf16 in LDS: 4608 float2 loads
    for (int i = tid; i < PK * (C_DIM / 2); i += 256) {
        const int n  = i >> 5;           // W row (0..143)
        const int k2 = i & 31;           // float2 index within row
        const float2 w2 = ((const float2*)W)[i];
        const int o = n * ZSTRIDE + k2 * 2;
        const ushort h0 = f2bf(w2.x);
        const ushort h1 = f2bf(w2.y);
        w_hi[o]     = h0;
        w_hi[o + 1] = h1;
        w_lo[o]     = f2bf(w2.x - bf2f(h0));
        w_lo[o + 1] = f2bf(w2.y - bf2f(h1));
    }
    __syncthreads();

    const int lane = tid & 63;
    const int wv   = tid >> 6;    // wave -> m-subtile (16 rows)
    const int col  = lane & 15;   // A row within tile / B,C/D column
    const int kg   = lane >> 4;   // k-group 0..3

    // A operand: lane supplies x[arow][kg*8 + e (+32*chunk)], split hi/lo.
    const int arow = block_row + wv * 16 + col;
    const float* xr = x + (size_t)(arow < N ? arow : 0) * C_DIM;
    float4 x0 = ((const float4*)xr)[kg * 2];
    float4 x1 = ((const float4*)xr)[kg * 2 + 1];
    float4 x2 = ((const float4*)xr)[8 + kg * 2];
    float4 x3 = ((const float4*)xr)[8 + kg * 2 + 1];
    if (arow >= N) {
        x0 = x1 = x2 = x3 = make_float4(0.f, 0.f, 0.f, 0.f);
    }

    short8v a_hi0, a_lo0, a_hi1, a_lo1;
    {
        const float t0[8] = {x0.x, x0.y, x0.z, x0.w, x1.x, x1.y, x1.z, x1.w};
        const float t1[8] = {x2.x, x2.y, x2.z, x2.w, x3.x, x3.y, x3.z, x3.w};
        #pragma unroll
        for (int e = 0; e < 8; ++e) {
            const ushort h = f2bf(t0[e]);
            a_hi0[e] = (short)h;
            a_lo0[e] = (short)f2bf(t0[e] - bf2f(h));
            const ushort g = f2bf(t1[e]);
            a_hi1[e] = (short)g;
            a_lo1[e] = (short)f2bf(t1[e] - bf2f(g));
        }
    }

    // C/D layout (HW-verified): col = lane&15, row = kg*4 + reg
    const int orow0 = block_row + wv * 16 + kg * 4;

    #pragma unroll
    for (int nt = 0; nt < 9; ++nt) {
        const ushort* bhp = &w_hi[(nt * 16 + col) * ZSTRIDE + kg * 8];
        const ushort* blp = &w_lo[(nt * 16 + col) * ZSTRIDE + kg * 8];
        const short8v bh0 = *(const short8v*)bhp;          // k chunk 0
        const short8v bh1 = *(const short8v*)(bhp + 32);   // k chunk 1
        const short8v bl0 = *(const short8v*)blp;
        const short8v bl1 = *(const short8v*)(blp + 32);

        f32x4 acc = {0.f, 0.f, 0.f, 0.f};
        // split-bf16 3-product: lo terms first, hi*hi last
        acc = __builtin_amdgcn_mfma_f32_16x16x32_bf16(a_lo0, bh0, acc, 0, 0, 0);
        acc = __builtin_amdgcn_mfma_f32_16x16x32_bf16(a_hi0, bl0, acc, 0, 0, 0);
        acc = __builtin_amdgcn_mfma_f32_16x16x32_bf16(a_lo1, bh1, acc, 0, 0, 0);
        acc = __builtin_amdgcn_mfma_f32_16x16x32_bf16(a_hi1, bl1, acc, 0, 0, 0);
        acc = __builtin_amdgcn_mfma_f32_16x16x32_bf16(a_hi0, bh0, acc, 0, 0, 0);
        acc = __builtin_amdgcn_mfma_f32_16x16x32_bf16(a_hi1, bh1, acc, 0, 0, 0);

        #pragma unroll
        for (int r = 0; r < 4; ++r) {
            const int row = orow0 + r;
            if (row < N) Zb[(size_t)row * PK + nt * 16 + col] = f2bf(acc[r]);
        }
    }
}

// ---------------------------------------------------------------------------
// Kernel 2: edge messages + scatter-add (unsorted).
// thread-slot = (eg, p); 16 lanes share an edge; 8 edges per slot.
// USEBF: pose read as packed bf16 (4B/lane) when the workspace table exists;
// otherwise float2 (8B/lane) straight from the input.
// ---------------------------------------------------------------------------
#define EILP 8
template <bool USEBF>
__global__ __launch_bounds__(256) void edge_kernel(const int* __restrict__ ei,
                                                   const float* __restrict__ pos,
                                                   const float* __restrict__ pose,
                                                   const uint* __restrict__ pose_bf,
                                                   const ushort* __restrict__ Zb,
                                                   float* __restrict__ out,
                                                   int E) {
    const int p  = threadIdx.x & 15;
    const int eg = threadIdx.x >> 4;
    const int e0 = blockIdx.x * (16 * EILP) + eg;

    int  r[EILP], c[EILP];
    bool valid[EILP];
    #pragma unroll
    for (int it = 0; it < EILP; ++it) {
        int e = e0 + it * 16;
        valid[it] = (e < E);
        int ec = valid[it] ? e : 0;
        r[it] = ei[ec];
        c[it] = ei[E + ec];
    }

    float d0[EILP], d1[EILP];
    #pragma unroll
    for (int it = 0; it < EILP; ++it) {
        const float2 pc = ((const float2*)pos)[c[it]];
        const float2 pr = ((const float2*)pos)[r[it]];
        d0[it] = (pc.x - pr.x) * INV2S;
        d1[it] = (pc.y - pr.y) * INV2S;
    }

    float a_[EILP], b_[EILP];
    #pragma unroll
    for (int it = 0; it < EILP; ++it) {
        if (USEBF) {
            const uint ab = pose_bf[(size_t)r[it] * P_DIM + p];
            a_[it] = bf2f((ushort)(ab & 0xffffu));
            b_[it] = bf2f((ushort)(ab >> 16));
        } else {
            const float2 ab = ((const float2*)pose)[(size_t)r[it] * P_DIM + p];
            a_[it] = ab.x;
            b_[it] = ab.y;
        }
    }

    #pragma unroll
    for (int it = 0; it < EILP; ++it) {
        const float p0 = fmaf(a_[it], d0[it], fmaf(-b_[it], d1[it], 0.5f));
        const float p1 = fmaf(b_[it], d0[it], fmaf( a_[it], d1[it], 0.5f));

        const float v0 = fminf(fmaxf(p0, 0.0f), 1.0f) * 2.0f;
        const float v1 = fminf(fmaxf(p1, 0.0f), 1.0f) * 2.0f;
        const float lo0 = floorf(v0);
        const float lo1 = floorf(v1);
        const float f0 = v0 - lo0;
        const float f1 = v1 - lo1;
        const int i00 = min((int)lo0, 2);
        const int i01 = min((int)lo0 + 1, 2);
        const int i10 = min((int)lo1, 2);
        const int i11 = min((int)lo1 + 1, 2);

        const ushort* __restrict__ Zp = Zb + (size_t)c[it] * PK + p * K_DIM;
        const float w00 = (1.0f - f0) * (1.0f - f1);
        const float w01 = (1.0f - f0) * f1;
        const float w10 = f0 * (1.0f - f1);
        const float w11 = f0 * f1;

        float m = w00 * bf2f(Zp[i00 + 3 * i10]);
        m = fmaf(w01, bf2f(Zp[i00 + 3 * i11]), m);
        m = fmaf(w10, bf2f(Zp[i01 + 3 * i10]), m);
        m = fmaf(w11, bf2f(Zp[i01 + 3 * i11]), m);

        if (valid[it]) atomicAdd(&out[(size_t)r[it] * P_DIM + p], m);
    }
}

// ---------------------------------------------------------------------------
extern "C" void kernel_launch(void* const* d_in, const int* in_sizes, int n_in,
                              void* d_out, int out_size, void* d_ws, size_t ws_size,
                              hipStream_t stream) {
    const float* x    = (const float*)d_in[0];
    const float* pos  = (const float*)d_in[1];
    const float* pose = (const float*)d_in[2];
    const float* W    = (const float*)d_in[3];
    const float* bias = (const float*)d_in[4];
    const int*   ei   = (const int*)d_in[5];

    const int N = in_sizes[0] / C_DIM;   // 50000
    const int E = in_sizes[5] / 2;       // 800000

    float* out = (float*)d_out;
    ushort* Zb = (ushort*)d_ws;          // N*144 bf16 = 14.4 MB

    // pose-bf16 table only if the workspace actually has room for it
    const size_t zb_bytes   = (size_t)N * PK * sizeof(ushort);
    const size_t pose_bytes = (size_t)N * P_DIM * sizeof(uint);
    uint* pose_bf = (ws_size >= zb_bytes + pose_bytes)
                        ? (uint*)((char*)d_ws + zb_bytes) : nullptr;

    z_gemm_kernel<<<(N + 63) / 64, 256, 0, stream>>>(x, W, bias, pose, out, Zb, pose_bf, N);

    const int eblocks = (E + 16 * EILP - 1) / (16 * EILP);
    if (pose_bf != nullptr)
        edge_kernel<true><<<eblocks, 256, 0, stream>>>(ei, pos, pose, pose_bf, Zb, out, E);
    else
        edge_kernel<false><<<eblocks, 256, 0, stream>>>(ei, pos, pose, pose_bf, Zb, out, E);
}